// Round 4
// baseline (1234.706 us; speedup 1.0000x reference)
//
#include <hip/hip_runtime.h>
#include <math.h>

#define H 10
#define BATCH 16384
#define NPAIRS 1024   // T/2
#define EPW 6         // sequences per 64-lane wave, 60 active lanes

#define LOG2E 1.44269504088896340736f

#if __has_builtin(__builtin_amdgcn_exp2f)
#define EXP2(x) __builtin_amdgcn_exp2f(x)
#else
#define EXP2(x) exp2f(x)
#endif

__device__ __forceinline__ float fast_rcp(float x) { return __builtin_amdgcn_rcpf(x); }

// waves_per_eu(3,3): pins min AND max occupancy => register budget 512/3≈170,
// and the allocator's occupancy heuristic (which parked 88 weights in AGPRs at
// VGPR_Count=72..76 in rounds 2-3, costing ~90 v_accvgpr_read per pair) is
// disabled. Grid is 2731 waves = 10.7/CU < 12 capacity => all resident.
__global__ void __attribute__((amdgpu_flat_work_group_size(64, 64),
                               amdgpu_waves_per_eu(3, 3)))
lstm_kernel(const float* __restrict__ x,
            const float* __restrict__ WihA, const float* __restrict__ WhhA,
            const float* __restrict__ bihA, const float* __restrict__ bhhA,
            const float* __restrict__ WihB, const float* __restrict__ WhhB,
            const float* __restrict__ bihB, const float* __restrict__ bhhB,
            const float* __restrict__ Wlin, const float* __restrict__ blin,
            float* __restrict__ out)
{
    const int lane    = threadIdx.x;          // block = 1 wave
    const int e_local = lane / H;             // 0..6 (6 => spare lanes)
    const int j       = lane - e_local * H;   // hidden unit owned by this lane
    const bool active = lane < EPW * H;
    const int elem    = blockIdx.x * EPW + e_local;
    const bool valid  = active && (elem < BATCH);
    const int jj      = active ? j : 0;
    const int elem_c  = valid ? elem : 0;

    // Per-lane weights in registers: lane j owns gate rows {j, H+j, 2H+j, 3H+j}.
    // Pre-scaled: sigmoid gates (i,f,o) by -log2e, tanh gate (g) by +2log2e,
    // so all activations use raw exp2.
    float wA[4][H], wB[4][H];
    float bA[4], bB[4], wxA0[4], wxA1[4], wxB[4];
#pragma unroll
    for (int g = 0; g < 4; ++g) {
        const float s = (g == 2) ? (2.0f * LOG2E) : (-LOG2E);
        const int row = g * H + jj;
        bA[g]   = s * (bihA[row] + bhhA[row]);
        bB[g]   = s * (bihB[row] + bhhB[row]);
        wxA0[g] = s * WihA[row * 2 + 0];
        wxA1[g] = s * WihA[row * 2 + 1];
        wxB[g]  = s * WihB[row];
#pragma unroll
        for (int k = 0; k < H; ++k) {
            wA[g][k] = s * WhhA[row * H + k];
            wB[g][k] = s * WhhB[row * H + k];
        }
    }
    // Pin weights as opaque register values (defeats in-loop rematerialization).
#pragma unroll
    for (int g = 0; g < 4; ++g) {
        asm volatile("" : "+v"(bA[g]), "+v"(bB[g]), "+v"(wxA0[g]),
                          "+v"(wxA1[g]), "+v"(wxB[g]));
#pragma unroll
        for (int k = 0; k < H; ++k) {
            asm volatile("" : "+v"(wA[g][k]), "+v"(wB[g][k]));
        }
    }

    const int base4 = (e_local * H) << 2;     // bpermute byte addr of group base
    const float4* __restrict__ xr = (const float4*)x + (size_t)elem_c * NPAIRS;

    float h = 0.0f, c = 0.0f;

    auto do_pair = [&](const float4 xp) {
        // ================= cell B: input = x[:, 2p, :1] =================
        {
            float y0 = fmaf(wxB[0], xp.x, bB[0]);   // i (scaled -log2e)
            float y1 = fmaf(wxB[1], xp.x, bB[1]);   // f (scaled -log2e)
            float y2 = fmaf(wxB[2], xp.x, bB[2]);   // g (scaled +2log2e)
            float y3 = fmaf(wxB[3], xp.x, bB[3]);   // o (scaled -log2e)
#pragma unroll
            for (int k = 0; k < H; ++k) {
                const float hk = __int_as_float(
                    __builtin_amdgcn_ds_bpermute(base4 + (k << 2), __float_as_int(h)));
                y0 = fmaf(wB[0][k], hk, y0);
                y1 = fmaf(wB[1][k], hk, y1);
                y2 = fmaf(wB[2][k], hk, y2);
                y3 = fmaf(wB[3][k], hk, y3);
            }
            // fused: sigm(f)*c + sigm(i)*tanh(g)   [single rcp for the i*g term]
            const float ef = EXP2(y1);
            const float ei = EXP2(y0);
            const float eg = EXP2(-__builtin_fabsf(y2));
            const float sf = fast_rcp(1.0f + ef);
            const float d1 = (1.0f + ei) * (1.0f + eg);
            const float it = __builtin_copysignf((1.0f - eg) * fast_rcp(d1), y2);
            const float cn = fmaf(sf, c, it);
            // fused: sigm(o)*tanh(c)               [single rcp]
            const float eo = EXP2(y3);
            const float ec = EXP2((-2.0f * LOG2E) * __builtin_fabsf(cn));
            const float d2 = (1.0f + eo) * (1.0f + ec);
            h = __builtin_copysignf((1.0f - ec) * fast_rcp(d2), cn);
            c = cn;
        }
        // ================= cell A: input = x[:, 2p+1, :] =================
        {
            float y0 = fmaf(wxA1[0], xp.w, fmaf(wxA0[0], xp.z, bA[0]));
            float y1 = fmaf(wxA1[1], xp.w, fmaf(wxA0[1], xp.z, bA[1]));
            float y2 = fmaf(wxA1[2], xp.w, fmaf(wxA0[2], xp.z, bA[2]));
            float y3 = fmaf(wxA1[3], xp.w, fmaf(wxA0[3], xp.z, bA[3]));
#pragma unroll
            for (int k = 0; k < H; ++k) {
                const float hk = __int_as_float(
                    __builtin_amdgcn_ds_bpermute(base4 + (k << 2), __float_as_int(h)));
                y0 = fmaf(wA[0][k], hk, y0);
                y1 = fmaf(wA[1][k], hk, y1);
                y2 = fmaf(wA[2][k], hk, y2);
                y3 = fmaf(wA[3][k], hk, y3);
            }
            const float ef = EXP2(y1);
            const float ei = EXP2(y0);
            const float eg = EXP2(-__builtin_fabsf(y2));
            const float sf = fast_rcp(1.0f + ef);
            const float d1 = (1.0f + ei) * (1.0f + eg);
            const float it = __builtin_copysignf((1.0f - eg) * fast_rcp(d1), y2);
            const float cn = fmaf(sf, c, it);
            const float eo = EXP2(y3);
            const float ec = EXP2((-2.0f * LOG2E) * __builtin_fabsf(cn));
            const float d2 = (1.0f + eo) * (1.0f + ec);
            h = __builtin_copysignf((1.0f - ec) * fast_rcp(d2), cn);
            c = cn;
        }
    };

    // Peeled prefetch loop: unconditional xr[p+1] load (no clamp cndmask),
    // last pair handled after the loop.
    float4 xp = xr[0];
#pragma unroll 2
    for (int p = 0; p < NPAIRS - 1; ++p) {
        const float4 xnext = xr[p + 1];       // off the critical h->h chain
        do_pair(xp);
        xp = xnext;
    }
    do_pair(xp);

    // ---- output: sigmoid(h . Wlin + blin), reduce across the 10-lane group ----
    const float v = Wlin[jj] * h;
    float s = v;
#pragma unroll
    for (int k = 1; k < H; ++k) {
        s += __int_as_float(
            __builtin_amdgcn_ds_bpermute(base4 + (k << 2), __float_as_int(v)));
    }
    if (valid && j == 0) {
        const float y = s + blin[0];
        out[elem] = fast_rcp(1.0f + EXP2(-LOG2E * y));
    }
}

extern "C" void kernel_launch(void* const* d_in, const int* in_sizes, int n_in,
                              void* d_out, int out_size, void* d_ws, size_t ws_size,
                              hipStream_t stream) {
    const float* x    = (const float*)d_in[0];
    const float* WihA = (const float*)d_in[1];
    const float* WhhA = (const float*)d_in[2];
    const float* bihA = (const float*)d_in[3];
    const float* bhhA = (const float*)d_in[4];
    const float* WihB = (const float*)d_in[5];
    const float* WhhB = (const float*)d_in[6];
    const float* bihB = (const float*)d_in[7];
    const float* bhhB = (const float*)d_in[8];
    const float* Wlin = (const float*)d_in[9];
    const float* blin = (const float*)d_in[10];
    float* out = (float*)d_out;

    const int grid = (BATCH + EPW - 1) / EPW;  // 2731 one-wave blocks
    hipLaunchKernelGGL(lstm_kernel, dim3(grid), dim3(64), 0, stream,
                       x, WihA, WhhA, bihA, bhhA, WihB, WhhB, bihB, bhhB,
                       Wlin, blin, out);
}

// Round 5
// 1210.267 us; speedup vs baseline: 1.0202x; 1.0202x over previous
//
#include <hip/hip_runtime.h>
#include <math.h>

#define H 10
#define BATCH 16384
#define NPAIRS 1024   // T/2
#define EPW 6         // sequences per 64-lane wave, 60 active lanes

#define LOG2E 1.44269504088896340736f

#if __has_builtin(__builtin_amdgcn_exp2f)
#define EXP2(x) __builtin_amdgcn_exp2f(x)
#else
#define EXP2(x) exp2f(x)
#endif

typedef _Float16 half_t;
typedef _Float16 __attribute__((ext_vector_type(2))) half2_t;

__device__ __forceinline__ float fast_rcp(float x) { return __builtin_amdgcn_rcpf(x); }

// Extract half (k&1) of a packed pair stored as float bits, widen to f32.
// Pattern (extractelement + fpext + fma) folds to v_fma_mix_f32 on gfx9+.
__device__ __forceinline__ float half_of(float packed, int idx) {
    half2_t p = __builtin_bit_cast(half2_t, packed);
    return (float)p[idx];
}

__global__ void __launch_bounds__(64, 2)
lstm_kernel(const float* __restrict__ x,
            const float* __restrict__ WihA, const float* __restrict__ WhhA,
            const float* __restrict__ bihA, const float* __restrict__ bhhA,
            const float* __restrict__ WihB, const float* __restrict__ WhhB,
            const float* __restrict__ bihB, const float* __restrict__ bhhB,
            const float* __restrict__ Wlin, const float* __restrict__ blin,
            float* __restrict__ out)
{
    const int lane    = threadIdx.x;          // block = 1 wave
    const int e_local = lane / H;             // 0..6 (6 => spare lanes)
    const int j       = lane - e_local * H;   // hidden unit owned by this lane
    const bool active = lane < EPW * H;
    const int elem    = blockIdx.x * EPW + e_local;
    const bool valid  = active && (elem < BATCH);
    const int jj      = active ? j : 0;
    const int elem_c  = valid ? elem : 0;

    // Lane j owns gate rows {j, H+j, 2H+j, 3H+j}. Whh weights are stored as
    // PACKED F16 PAIRS (40 VGPRs instead of 80): rounds 1-4 showed the
    // allocator refuses to keep ~97 fp32 weights in arch VGPRs (VGPR_Count
    // pinned at 72-76, ~345 cyc/pair of spill round-trips). f16 halves the
    // footprint; v_fma_mix_f32 consumes the halves at fp32-accumulate
    // precision with the same 2-cycle issue as v_fma_f32.
    // Pre-scaled: sigmoid gates (i,f,o) by -log2e, tanh gate (g) by +2log2e.
    float wA2[4][5], wB2[4][5];               // float-bit-pattern of half2
    float bA[4], bB[4], wxA0[4], wxA1[4], wxB[4];
#pragma unroll
    for (int g = 0; g < 4; ++g) {
        const float s = (g == 2) ? (2.0f * LOG2E) : (-LOG2E);
        const int row = g * H + jj;
        bA[g]   = s * (bihA[row] + bhhA[row]);
        bB[g]   = s * (bihB[row] + bhhB[row]);
        wxA0[g] = s * WihA[row * 2 + 0];
        wxA1[g] = s * WihA[row * 2 + 1];
        wxB[g]  = s * WihB[row];
#pragma unroll
        for (int k2 = 0; k2 < 5; ++k2) {
            half2_t pa, pb;
            pa[0] = (half_t)(s * WhhA[row * H + 2 * k2 + 0]);
            pa[1] = (half_t)(s * WhhA[row * H + 2 * k2 + 1]);
            pb[0] = (half_t)(s * WhhB[row * H + 2 * k2 + 0]);
            pb[1] = (half_t)(s * WhhB[row * H + 2 * k2 + 1]);
            wA2[g][k2] = __builtin_bit_cast(float, pa);
            wB2[g][k2] = __builtin_bit_cast(float, pb);
        }
    }
    // Pin as opaque register values (defeats rematerialization).
#pragma unroll
    for (int g = 0; g < 4; ++g) {
        asm volatile("" : "+v"(bA[g]), "+v"(bB[g]), "+v"(wxA0[g]),
                          "+v"(wxA1[g]), "+v"(wxB[g]));
#pragma unroll
        for (int k2 = 0; k2 < 5; ++k2) {
            asm volatile("" : "+v"(wA2[g][k2]), "+v"(wB2[g][k2]));
        }
    }

    const int base4 = (e_local * H) << 2;     // bpermute byte addr of group base
    const float4* __restrict__ xr = (const float4*)x + (size_t)elem_c * NPAIRS;

    float h = 0.0f, c = 0.0f;

    auto do_pair = [&](const float4 xp) {
        // ================= cell B: input = x[:, 2p, :1] =================
        {
            float y0 = fmaf(wxB[0], xp.x, bB[0]);   // i (scaled -log2e)
            float y1 = fmaf(wxB[1], xp.x, bB[1]);   // f (scaled -log2e)
            float y2 = fmaf(wxB[2], xp.x, bB[2]);   // g (scaled +2log2e)
            float y3 = fmaf(wxB[3], xp.x, bB[3]);   // o (scaled -log2e)
#pragma unroll
            for (int k = 0; k < H; ++k) {
                const float hk = __int_as_float(
                    __builtin_amdgcn_ds_bpermute(base4 + (k << 2), __float_as_int(h)));
                y0 = fmaf(half_of(wB2[0][k >> 1], k & 1), hk, y0);
                y1 = fmaf(half_of(wB2[1][k >> 1], k & 1), hk, y1);
                y2 = fmaf(half_of(wB2[2][k >> 1], k & 1), hk, y2);
                y3 = fmaf(half_of(wB2[3][k >> 1], k & 1), hk, y3);
            }
            // fused: sigm(f)*c + sigm(i)*tanh(g)   [single rcp for the i*g term]
            const float ef = EXP2(y1);
            const float ei = EXP2(y0);
            const float eg = EXP2(-__builtin_fabsf(y2));
            const float sf = fast_rcp(1.0f + ef);
            const float d1 = (1.0f + ei) * (1.0f + eg);
            const float it = __builtin_copysignf((1.0f - eg) * fast_rcp(d1), y2);
            const float cn = fmaf(sf, c, it);
            // fused: sigm(o)*tanh(c)               [single rcp]
            const float eo = EXP2(y3);
            const float ec = EXP2((-2.0f * LOG2E) * __builtin_fabsf(cn));
            const float d2 = (1.0f + eo) * (1.0f + ec);
            h = __builtin_copysignf((1.0f - ec) * fast_rcp(d2), cn);
            c = cn;
        }
        // ================= cell A: input = x[:, 2p+1, :] =================
        {
            float y0 = fmaf(wxA1[0], xp.w, fmaf(wxA0[0], xp.z, bA[0]));
            float y1 = fmaf(wxA1[1], xp.w, fmaf(wxA0[1], xp.z, bA[1]));
            float y2 = fmaf(wxA1[2], xp.w, fmaf(wxA0[2], xp.z, bA[2]));
            float y3 = fmaf(wxA1[3], xp.w, fmaf(wxA0[3], xp.z, bA[3]));
#pragma unroll
            for (int k = 0; k < H; ++k) {
                const float hk = __int_as_float(
                    __builtin_amdgcn_ds_bpermute(base4 + (k << 2), __float_as_int(h)));
                y0 = fmaf(half_of(wA2[0][k >> 1], k & 1), hk, y0);
                y1 = fmaf(half_of(wA2[1][k >> 1], k & 1), hk, y1);
                y2 = fmaf(half_of(wA2[2][k >> 1], k & 1), hk, y2);
                y3 = fmaf(half_of(wA2[3][k >> 1], k & 1), hk, y3);
            }
            const float ef = EXP2(y1);
            const float ei = EXP2(y0);
            const float eg = EXP2(-__builtin_fabsf(y2));
            const float sf = fast_rcp(1.0f + ef);
            const float d1 = (1.0f + ei) * (1.0f + eg);
            const float it = __builtin_copysignf((1.0f - eg) * fast_rcp(d1), y2);
            const float cn = fmaf(sf, c, it);
            const float eo = EXP2(y3);
            const float ec = EXP2((-2.0f * LOG2E) * __builtin_fabsf(cn));
            const float d2 = (1.0f + eo) * (1.0f + ec);
            h = __builtin_copysignf((1.0f - ec) * fast_rcp(d2), cn);
            c = cn;
        }
    };

    // Peeled prefetch loop: unconditional xr[p+1] load, last pair after loop.
    float4 xp = xr[0];
#pragma unroll 2
    for (int p = 0; p < NPAIRS - 1; ++p) {
        const float4 xnext = xr[p + 1];       // off the critical h->h chain
        do_pair(xp);
        xp = xnext;
    }
    do_pair(xp);

    // ---- output: sigmoid(h . Wlin + blin), reduce across the 10-lane group ----
    const float v = Wlin[jj] * h;
    float s = v;
#pragma unroll
    for (int k = 1; k < H; ++k) {
        s += __int_as_float(
            __builtin_amdgcn_ds_bpermute(base4 + (k << 2), __float_as_int(v)));
    }
    if (valid && j == 0) {
        const float y = s + blin[0];
        out[elem] = fast_rcp(1.0f + EXP2(-LOG2E * y));
    }
}

extern "C" void kernel_launch(void* const* d_in, const int* in_sizes, int n_in,
                              void* d_out, int out_size, void* d_ws, size_t ws_size,
                              hipStream_t stream) {
    const float* x    = (const float*)d_in[0];
    const float* WihA = (const float*)d_in[1];
    const float* WhhA = (const float*)d_in[2];
    const float* bihA = (const float*)d_in[3];
    const float* bhhA = (const float*)d_in[4];
    const float* WihB = (const float*)d_in[5];
    const float* WhhB = (const float*)d_in[6];
    const float* bihB = (const float*)d_in[7];
    const float* bhhB = (const float*)d_in[8];
    const float* Wlin = (const float*)d_in[9];
    const float* blin = (const float*)d_in[10];
    float* out = (float*)d_out;

    const int grid = (BATCH + EPW - 1) / EPW;  // 2731 one-wave blocks
    hipLaunchKernelGGL(lstm_kernel, dim3(grid), dim3(64), 0, stream,
                       x, WihA, WhhA, bihA, bhhA, WihB, WhhB, bihB, bhhB,
                       Wlin, blin, out);
}